// Round 5
// baseline (443.973 us; speedup 1.0000x reference)
//
#include <hip/hip_runtime.h>

#define EPS 1e-6f

typedef __attribute__((ext_vector_type(8))) __bf16 bf16x8;
typedef __attribute__((ext_vector_type(4))) float f32x4;
typedef __attribute__((ext_vector_type(4))) unsigned short us4v;
typedef __attribute__((ext_vector_type(8))) unsigned short us8v;
typedef unsigned short us;

__device__ inline us f2bf(float f) {
  unsigned int u = __builtin_bit_cast(unsigned int, f);
  unsigned int r = (u + 0x7fffu + ((u >> 16) & 1u)) >> 16;
  return (us)r;
}
__device__ inline float bf2f(us s) {
  unsigned int u = ((unsigned int)s) << 16;
  return __builtin_bit_cast(float, u);
}
// packed fp32->bf16 (RNE), lo=cvt(a), hi=cvt(b). No builtin on gfx950.
__device__ inline unsigned int cvtpk(float a, float b) {
  unsigned int d;
  asm("v_cvt_pk_bf16_f32 %0, %1, %2" : "=v"(d) : "v"(a), "v"(b));
  return d;
}

__device__ inline void gl_lds16(const us* g, us* l) {
  __builtin_amdgcn_global_load_lds(
      (const __attribute__((address_space(1))) unsigned int*)g,
      (__attribute__((address_space(3))) unsigned int*)l, 16, 0, 0);
}

#define STR_(x) #x
#define WAITV(n) asm volatile("s_waitcnt vmcnt(" STR_(n) ")" ::: "memory")

// ---------------------------------------------------------------------------
// weights fp32 -> bf16 (all four in one launch). grid 2048: bid>>9 = matrix.
// ---------------------------------------------------------------------------
__global__ __launch_bounds__(256) void conv_w4(const float* __restrict__ wq,
                                               const float* __restrict__ wk,
                                               const float* __restrict__ wv,
                                               const float* __restrict__ wo,
                                               us* __restrict__ dq,
                                               us* __restrict__ dk,
                                               us* __restrict__ dv,
                                               us* __restrict__ dwo) {
  int bid = blockIdx.x;
  int msel = bid >> 9, lb = bid & 511;
  const float* s = (msel == 0) ? wq : (msel == 1) ? wk : (msel == 2) ? wv : wo;
  us* d = (msel == 0) ? dq : (msel == 1) ? dk : (msel == 2) ? dv : dwo;
  int idx = lb * 256 + threadIdx.x;
  size_t base = (size_t)idx * 8;
  float4 a = *(const float4*)(s + base);
  float4 b = *(const float4*)(s + base + 4);
  us8v o;
  o[0] = f2bf(a.x); o[1] = f2bf(a.y); o[2] = f2bf(a.z); o[3] = f2bf(a.w);
  o[4] = f2bf(b.x); o[5] = f2bf(b.y); o[6] = f2bf(b.z); o[7] = f2bf(b.w);
  *(us8v*)(d + base) = o;
}

// ---------------------------------------------------------------------------
// Projection GEMM, 8-phase schedule, FUSED fp32->bf16 input conversion,
// with WINDOW-DEEP A prefetch (register double-buffer).
//   BM=BN=256, BK=64, 512 thr / 8 waves (2M x 4N), per-wave out 128x64.
//   LDS: As[2]/Bs[2] double-buffered K-tiles (bf16), 128 KiB.
//   B (weights, bf16): global_load_lds, staged 4-6 phases ahead (window m
//     stages B(m+2)).
//   A (activations): reg-staged with TWO register buffers avb[0/1]:
//     window m ISSUES A(m+2) loads (ph0/ph1) into avb[nxt], and WRITES
//     A(m+1) (loaded one window earlier, 4-6 phase margin ~1000+cyc > HBM
//     latency) from avb[cur] via v_cvt_pk_bf16_f32 + ds_write (ph2/ph3).
//     Buffer indices are macro literals (no runtime-indexed reg arrays).
//
// vmcnt ledger (fp32 X: 12 VM ops/window = 8 A-loads + 4 B-gl_lds):
//   V1 (ph2, before write A(m+1).h0): newer = A(m+1).h1(4)+B(m+1)(4)+
//       A(m+2)(8) = 16
//   V2 (ph3, before write A(m+1).h1): newer = B(m+1)(4)+A(m+2)(8)+
//       B(m+2).h0(2) = 14
//   V3 (ph3 end, publish tile m+1; needs B(m+1) landed): newer =
//       A(m+2)(8)+B(m+2)(4) = 12
//   tail w14 {8,4,0}, w15 {-,-,0}.  bf16 X (MODE 3, 2 loads/half):
//   steady {10,10,8}, w14 {6,4,0}.
// All waits leave newer loads in flight (never drain mid-loop). ds_writes
// drained by same-phase lgkmcnt(0) before the publish barrier; A-writes
// target As[(m+1)&1] while reads hit As[m&1] — disjoint. B(m+2) overwrites
// Bs[m&1] only after all waves' ph0 B-reads completed (2+ barriers prior).
//
// MODE 0: phi (elu+1), bf16 row-major      MODE 1: phi, bf16 per-head kt
// MODE 2: id, bf16 per-head vt             MODE 3: id, fp32 row-major (X bf16)
// grid 256 (1/CU), XCD-bijective swizzle: xcd=bid&7 owns 8 rowg x 4 colg.
// ---------------------------------------------------------------------------
template <int MODE>
__global__ __launch_bounds__(512, 2) void proj_gemm(const void* __restrict__ Xv,
                                                    const us* __restrict__ W,
                                                    const float* __restrict__ bias,
                                                    void* __restrict__ Yv) {
  constexpr bool FP32X = (MODE != 3);
  __shared__ alignas(16) us As[2][256 * 64];
  __shared__ alignas(16) us Bs[2][256 * 64];

  const float* Xf = (const float*)Xv;
  const us* Xh = (const us*)Xv;

  const int t = threadIdx.x;
  const int wave = t >> 6, lane = t & 63;
  const int q4 = lane >> 4, l16 = lane & 15;
  const int wm = wave >> 2, wn = wave & 3;   // 2(M) x 4(N) wave grid
  const int bid = blockIdx.x;
  const int rowg = (bid & 7) * 8 + (bid >> 5);  // 0..63
  const int colg = (bid >> 3) & 3;              // 0..3
  const int rowBase = rowg << 8;
  const int colBase = colg << 8;

  // staging geometry: thread t covers row (h*128 + r*64 + tr),
  // k-granule g8 = ((t&7)^(tr&7))*8 elems (pre-swizzled source, linear LDS).
  const int tr = t >> 3;
  const int g8 = ((t & 7) ^ (tr & 7)) * 8;
  const us* Wg = W + (size_t)(colBase + tr) * 1024 + g8;

  // read-side swizzled granule offsets (us), per k-slice ks=0/1
  const int gx0 = ((0 | q4) ^ (l16 & 7)) * 8;
  const int gx1 = ((4 | q4) ^ (l16 & 7)) * 8;
  const int arow_off = (wm * 128 + l16) * 64;
  const int brow_off = (wn * 64 + l16) * 64;

  float4 avb[2][2][2][2];  // [buf][half][round][slot]  (FP32X)
  uint4 awb[2][2][2];      // [buf][half][round]        (bf16)

  f32x4 acc[8][4];
#pragma unroll
  for (int i = 0; i < 8; i++)
#pragma unroll
    for (int j = 0; j < 4; j++) acc[i][j] = (f32x4){0.f, 0.f, 0.f, 0.f};

#define ISSUE_A(BUF, kt, h)                                                  \
  if constexpr (FP32X) {                                                     \
    const float* p_ = Xf + (size_t)(rowBase + (h) * 128 + tr) * 1024 +       \
                      (kt) * 64 + g8;                                        \
    avb[BUF][h][0][0] = *(const float4*)p_;                                  \
    avb[BUF][h][0][1] = *(const float4*)(p_ + 4);                            \
    avb[BUF][h][1][0] = *(const float4*)(p_ + 65536);                        \
    avb[BUF][h][1][1] = *(const float4*)(p_ + 65536 + 4);                    \
  } else {                                                                   \
    const us* p_ = Xh + (size_t)(rowBase + (h) * 128 + tr) * 1024 +          \
                   (kt) * 64 + g8;                                           \
    awb[BUF][h][0] = *(const uint4*)p_;                                      \
    awb[BUF][h][1] = *(const uint4*)(p_ + 65536);                            \
  }

#define WRITE_A(BUF, kt, h)                                                  \
  _Pragma("unroll") for (int r_ = 0; r_ < 2; ++r_) {                         \
    uint4 o_;                                                                \
    if constexpr (FP32X) {                                                   \
      o_.x = cvtpk(avb[BUF][h][r_][0].x, avb[BUF][h][r_][0].y);              \
      o_.y = cvtpk(avb[BUF][h][r_][0].z, avb[BUF][h][r_][0].w);              \
      o_.z = cvtpk(avb[BUF][h][r_][1].x, avb[BUF][h][r_][1].y);              \
      o_.w = cvtpk(avb[BUF][h][r_][1].z, avb[BUF][h][r_][1].w);              \
    } else {                                                                 \
      o_ = awb[BUF][h][r_];                                                  \
    }                                                                        \
    *(uint4*)&As[(kt) & 1][((h) * 128 + wave * 8) * 64 + r_ * 4096 +         \
                           lane * 8] = o_;                                   \
  }

#define STAGE_B(kt, h)                                                       \
  {                                                                          \
    us* d_ = &Bs[(kt) & 1][((h) * 128 + wave * 8) * 64];                     \
    const us* s_ = Wg + (size_t)((h) * 128) * 1024 + (kt) * 64;              \
    gl_lds16(s_, d_);                                                        \
    gl_lds16(s_ + (size_t)64 * 1024, d_ + 64 * 64);                          \
  }
#define RD_A(af, base)                                                       \
  _Pragma("unroll") for (int s_i = 0; s_i < 2; ++s_i) {                      \
    af[s_i][0] = *(const bf16x8*)(Ar + ((base) + s_i) * 1024 + gx0);         \
    af[s_i][1] = *(const bf16x8*)(Ar + ((base) + s_i) * 1024 + gx1);         \
  }
#define PH_SYNC_PRE()                                                        \
  asm volatile("s_barrier" ::: "memory");                                    \
  asm volatile("s_waitcnt lgkmcnt(0)" ::: "memory");                         \
  __builtin_amdgcn_sched_barrier(0);                                         \
  __builtin_amdgcn_s_setprio(1);
#define PH_SYNC_POST()                                                       \
  __builtin_amdgcn_s_setprio(0);                                            \
  asm volatile("s_barrier" ::: "memory");
#define MFMA16(J, AF)                                                        \
  _Pragma("unroll") for (int s_i = 0; s_i < 2; ++s_i)                        \
  _Pragma("unroll") for (int ks = 0; ks < 2; ++ks)                           \
  _Pragma("unroll") for (int ni = 0; ni < 4; ++ni)                           \
    acc[2 * (J) + s_i][ni] = __builtin_amdgcn_mfma_f32_16x16x32_bf16(        \
        AF[s_i][ks], bfv[ni][ks], acc[2 * (J) + s_i][ni], 0, 0, 0);

  // One K-window: phases 0-3. CUR/NXT/ISSA/WRA/STGB/V1/V2/V3 are literals.
#define WINDOW(m, CUR, NXT, ISSA, WRA, STGB, V1, V2, V3)                     \
  {                                                                          \
    const us* Ar = &As[(m) & 1][arow_off];                                   \
    const us* Br = &Bs[(m) & 1][brow_off];                                   \
    bf16x8 bfv[4][2];                                                        \
    { /* ph0: B-all + A-pair0 ; issue A(m+2).h0 */                           \
      bf16x8 af[2][2];                                                       \
      RD_A(af, 0);                                                           \
      _Pragma("unroll") for (int ni = 0; ni < 4; ++ni) {                     \
        bfv[ni][0] = *(const bf16x8*)(Br + ni * 1024 + gx0);                 \
        bfv[ni][1] = *(const bf16x8*)(Br + ni * 1024 + gx1);                 \
      }                                                                      \
      if (ISSA) { ISSUE_A(NXT, (m) + 2, 0); }                                \
      PH_SYNC_PRE(); MFMA16(0, af); PH_SYNC_POST();                          \
    }                                                                        \
    { /* ph1: A-pair1 ; issue A(m+2).h1 */                                   \
      bf16x8 af[2][2];                                                       \
      RD_A(af, 2);                                                           \
      if (ISSA) { ISSUE_A(NXT, (m) + 2, 1); }                                \
      PH_SYNC_PRE(); MFMA16(1, af); PH_SYNC_POST();                          \
    }                                                                        \
    { /* ph2: A-pair2 ; wait+write A(m+1).h0 ; gl_lds B(m+2).h0 */           \
      bf16x8 af[2][2];                                                       \
      RD_A(af, 4);                                                           \
      if (WRA) { WAITV(V1); WRITE_A(CUR, (m) + 1, 0); }                      \
      if (STGB) STAGE_B((m) + 2, 0);                                         \
      PH_SYNC_PRE(); MFMA16(2, af); PH_SYNC_POST();                          \
    }                                                                        \
    { /* ph3: A-pair3 ; wait+write A(m+1).h1 ; gl_lds B(m+2).h1 ; publish */ \
      bf16x8 af[2][2];                                                       \
      RD_A(af, 6);                                                           \
      if (WRA) { WAITV(V2); WRITE_A(CUR, (m) + 1, 1); }                      \
      if (STGB) STAGE_B((m) + 2, 1);                                         \
      asm volatile("s_barrier" ::: "memory");                                \
      asm volatile("s_waitcnt lgkmcnt(0)" ::: "memory");                     \
      __builtin_amdgcn_sched_barrier(0);                                     \
      __builtin_amdgcn_s_setprio(1);                                         \
      MFMA16(3, af);                                                         \
      __builtin_amdgcn_s_setprio(0);                                         \
      WAITV(V3);                                                             \
      asm volatile("s_barrier" ::: "memory");                                \
    }                                                                        \
  }

  // ---- prologue: A(0)->avb[0], B(0), A(1)->avb[1], B(1) ----
  ISSUE_A(0, 0, 0); ISSUE_A(0, 0, 1);
  STAGE_B(0, 0); STAGE_B(0, 1);
  ISSUE_A(1, 1, 0); ISSUE_A(1, 1, 1);
  STAGE_B(1, 0); STAGE_B(1, 1);
  if constexpr (FP32X) {
    WAITV(16);                     // A(0) landed (newer: B0(4)+A1(8)+B1(4))
    WRITE_A(0, 0, 0); WRITE_A(0, 0, 1);
    WAITV(12);                     // B(0) landed (newer: A1(8)+B1(4))
  } else {
    WAITV(12);                     // A(0) landed (newer: B0(4)+A1(4)+B1(4))
    WRITE_A(0, 0, 0); WRITE_A(0, 0, 1);
    WAITV(8);                      // B(0) landed (newer: A1(4)+B1(4))
  }
  asm volatile("s_waitcnt lgkmcnt(0)" ::: "memory");
  asm volatile("s_barrier" ::: "memory");

  // ---- main: windows 0..13 steady, 14/15 tail ----
  if constexpr (FP32X) {
    for (int mb = 0; mb < 7; ++mb) {
      const int m = 2 * mb;
      WINDOW(m, 1, 0, 1, 1, 1, 16, 14, 12);
      WINDOW(m + 1, 0, 1, 1, 1, 1, 16, 14, 12);
    }
    WINDOW(14, 1, 0, 0, 1, 0, 8, 4, 0);
    WINDOW(15, 0, 1, 0, 0, 0, 0, 0, 0);
  } else {
    for (int mb = 0; mb < 7; ++mb) {
      const int m = 2 * mb;
      WINDOW(m, 1, 0, 1, 1, 1, 10, 10, 8);
      WINDOW(m + 1, 0, 1, 1, 1, 1, 10, 10, 8);
    }
    WINDOW(14, 1, 0, 0, 1, 0, 6, 4, 0);
    WINDOW(15, 0, 1, 0, 0, 0, 0, 0, 0);
  }
#undef WINDOW
#undef ISSUE_A
#undef WRITE_A
#undef STAGE_B
#undef RD_A
#undef PH_SYNC_PRE
#undef PH_SYNC_POST
#undef MFMA16

  // epilogue
#pragma unroll
  for (int j = 0; j < 4; j++) {
    int col = colBase + wn * 64 + j * 16 + l16;
    float bv = bias[col];
#pragma unroll
    for (int i = 0; i < 8; i++) {
      int row0 = rowBase + wm * 128 + i * 16 + q4 * 4;
      if (MODE == 1 || MODE == 2) {
        int bb = row0 >> 12, m0 = row0 & 4095;
        int h = col >> 6, dd = col & 63;
        us4v pk;
#pragma unroll
        for (int r = 0; r < 4; r++) {
          float y = acc[i][j][r] + bv;
          if (MODE == 1) y = (y > 0.f) ? (y + 1.f) : __expf(y);
          pk[r] = f2bf(y);
        }
        *(us4v*)&((us*)Yv)[(((size_t)((bb * 16 + h) * 64 + dd)) << 12) + m0] = pk;
      } else {
#pragma unroll
        for (int r = 0; r < 4; r++) {
          float y = acc[i][j][r] + bv;
          if (MODE == 0) {
            y = (y > 0.f) ? (y + 1.f) : __expf(y);
            ((us*)Yv)[(size_t)(row0 + r) * 1024 + col] = f2bf(y);
          } else {
            ((float*)Yv)[(size_t)(row0 + r) * 1024 + col] = y;
          }
        }
      }
    }
  }
}

// ---------------------------------------------------------------------------
// kv stage 1: partial kv_t[e][d] = sum_m vt[e][m]*kt[d][m] over a 1024-m slab,
// plus z-partials folded from the kt B-fragments. 256 blocks (bh x 4 splits),
// 4 waves each covering 256 m. LDS tree-reduce, plain stores (no atomics).
// ---------------------------------------------------------------------------
__global__ __launch_bounds__(256) void kv_stage1(const us* __restrict__ kt,
                                                 const us* __restrict__ vt,
                                                 float* __restrict__ part,
                                                 float* __restrict__ zpart) {
  __shared__ float red[4][4096];
  __shared__ float zred[4][64][4];

  const int blk = blockIdx.x;
  const int bh = blk >> 2, split = blk & 3;
  const int t = threadIdx.x;
  const int w = t >> 6, lane = t & 63;
  const int q4 = lane >> 4, l16 = lane & 15;
  const us* ktb = kt + (size_t)bh * 64 * 4096;
  const us* vtb = vt + (size_t)bh * 64 * 4096;
  const int mbeg = split * 1024 + w * 256;

  f32x4 acc[4][4];
#pragma unroll
  for (int i = 0; i < 4; i++)
#pragma unroll
    for (int j = 0; j < 4; j++) acc[i][j] = (f32x4){0.f, 0.f, 0.f, 0.f};
  float zacc[4] = {0.f, 0.f, 0.f, 0.f};

  for (int m0 = mbeg; m0 < mbeg + 256; m0 += 32) {
    bf16x8 af[4], bfr[4];
#pragma unroll
    for (int i = 0; i < 4; i++)
      af[i] = *(const bf16x8*)&vtb[(size_t)(i * 16 + l16) * 4096 + m0 + q4 * 8];
#pragma unroll
    for (int j = 0; j < 4; j++) {
      us8v ub = *(const us8v*)&ktb[(size_t)(j * 16 + l16) * 4096 + m0 + q4 * 8];
      bfr[j] = __builtin_bit_cast(bf16x8, ub);
#pragma unroll
      for (int e = 0; e < 8; e++) zacc[j] += bf2f(ub[e]);
    }
#pragma unroll
    for (int i = 0; i < 4; i++)
#pragma unroll
      for (int j = 0; j < 4; j++)
        acc[i][j] = __builtin_amdgcn_mfma_f32_16x16x32_bf16(af[i], bfr[j], acc[i][j], 0, 0, 0);
  }

#pragma unroll
  for (int i = 0; i < 4; i++)
#pragma unroll
    for (int j = 0; j < 4; j++)
#pragma unroll
      for (int r = 0; r < 4; r++)
        red[w][(i * 16 + q4 * 4 + r) * 64 + j * 16 + l16] = acc[i][j][r];
#pragma unroll
  for (int j = 0; j < 4; j++) zred[w][j * 16 + l16][q4] = zacc[j];
  __syncthreads();

  float* pb = part + (size_t)blk * 4096;
#pragma unroll
  for (int i = 0; i < 16; i++) {
    int idx = t + 256 * i;
    pb[idx] = red[0][idx] + red[1][idx] + red[2][idx] + red[3][idx];
  }
  if (t < 64) {
    float s = 0.f;
#pragma unroll
    for (int w2 = 0; w2 < 4; w2++)
#pragma unroll
      for (int q = 0; q < 4; q++) s += zred[w2][t][q];
    zpart[blk * 64 + t] = s;
  }
}

// stage 2: reduce the 4 split-partials -> kv bf16 + z fp32. 64 blocks.
__global__ __launch_bounds__(256) void kv_stage2(const float* __restrict__ part,
                                                 const float* __restrict__ zpart,
                                                 us* __restrict__ kvb,
                                                 float* __restrict__ z) {
  const int bh = blockIdx.x;
  const int t = threadIdx.x;
  const float* p0 = part + (size_t)bh * 4 * 4096;
#pragma unroll
  for (int i = 0; i < 16; i++) {
    int idx = t + 256 * i;
    float s = p0[idx] + p0[4096 + idx] + p0[8192 + idx] + p0[12288 + idx];
    kvb[(size_t)bh * 4096 + idx] = f2bf(s);
  }
  if (t < 64) {
    const float* zp = zpart + (size_t)bh * 4 * 64;
    z[bh * 64 + t] = zp[t] + zp[64 + t] + zp[128 + t] + zp[192 + t];
  }
}

// ---------------------------------------------------------------------------
// attn[b][n][h*64+e] = (sum_d q[n][d] kv[d][e]) / (q[n]·z + eps), bf16,
// written IN PLACE over q (each block reads exactly the region it writes).
// ---------------------------------------------------------------------------
__global__ __launch_bounds__(256) void attn_kernel(const us* __restrict__ q,
                                                   const us* __restrict__ kvb,
                                                   const float* __restrict__ z,
                                                   us* __restrict__ attn) {
  __shared__ alignas(16) us kvs[64 * 72];
  __shared__ float zs[64];
  __shared__ float invden[256];

  const int bid = blockIdx.x;
  const int bh = bid >> 4, nc = bid & 15;
  const int b = bh >> 4, h = bh & 15;
  const int n0 = nc * 256;
  const int t = threadIdx.x;
  const int wave = t >> 6, lane = t & 63;
  const int q4 = lane >> 4, l16 = lane & 15;

#pragma unroll
  for (int i = 0; i < 2; i++) {
    int chunk = t + 256 * i;          // 0..511
    int e = chunk >> 3, d8 = chunk & 7;
    us8v vv = *(const us8v*)&kvb[(size_t)bh * 4096 + chunk * 8];
    *(us8v*)&kvs[e * 72 + d8 * 8] = vv;
  }
  if (t < 64) zs[t] = z[bh * 64 + t];
  __syncthreads();

  {
    const us* qrow = q + ((size_t)(b * 4096 + n0 + t)) * 1024 + h * 64;
    float s = 0.f;
#pragma unroll
    for (int d0 = 0; d0 < 64; d0 += 8) {
      us8v v = *(const us8v*)(qrow + d0);
#pragma unroll
      for (int j = 0; j < 8; j++) s += bf2f(v[j]) * zs[d0 + j];
    }
    invden[t] = 1.0f / (s + EPS);
  }
  __syncthreads();

  f32x4 acc[4][4];
#pragma unroll
  for (int i = 0; i < 4; i++)
#pragma unroll
    for (int j = 0; j < 4; j++) acc[i][j] = (f32x4){0.f, 0.f, 0.f, 0.f};

  const us* qb = q + ((size_t)(b * 4096 + n0 + wave * 64)) * 1024 + h * 64;
#pragma unroll
  for (int ks = 0; ks < 2; ks++) {
    bf16x8 af[4], bfr[4];
#pragma unroll
    for (int i = 0; i < 4; i++)
      af[i] = *(const bf16x8*)(qb + (size_t)(i * 16 + l16) * 1024 + ks * 32 + q4 * 8);
#pragma unroll
    for (int j = 0; j < 4; j++)
      bfr[j] = *(const bf16x8*)&kvs[(j * 16 + l16) * 72 + ks * 32 + q4 * 8];
#pragma unroll
    for (int i = 0; i < 4; i++)
#pragma unroll
      for (int j = 0; j < 4; j++)
        acc[i][j] = __builtin_amdgcn_mfma_f32_16x16x32_bf16(af[i], bfr[j], acc[i][j], 0, 0, 0);
  }

  us* ab = attn + ((size_t)(b * 4096 + n0 + wave * 64)) * 1024 + h * 64;
#pragma unroll
  for (int i = 0; i < 4; i++)
#pragma unroll
    for (int j = 0; j < 4; j++)
#pragma unroll
      for (int r = 0; r < 4; r++) {
        int rowl = i * 16 + q4 * 4 + r;
        int nl = wave * 64 + rowl;
        int e = j * 16 + l16;
        ab[(size_t)rowl * 1024 + e] = f2bf(acc[i][j][r] * invden[nl]);
      }
}

// ---------------------------------------------------------------------------
extern "C" void kernel_launch(void* const* d_in, const int* in_sizes, int n_in,
                              void* d_out, int out_size, void* d_ws, size_t ws_size,
                              hipStream_t stream) {
  const float* queries = (const float*)d_in[0];
  const float* keys    = (const float*)d_in[1];
  const float* values  = (const float*)d_in[2];
  const float* wq = (const float*)d_in[3];
  const float* bq = (const float*)d_in[4];
  const float* wk = (const float*)d_in[5];
  const float* bk = (const float*)d_in[6];
  const float* wv = (const float*)d_in[7];
  const float* bv = (const float*)d_in[8];
  const float* wo = (const float*)d_in[9];
  const float* bo = (const float*)d_in[10];

  char* ws = (char*)d_ws;
  const size_t TB = (size_t)16384 * 1024 * 2;   // 33.55 MB per big bf16 buffer
  us* A   = (us*)(ws);            // kt, later q/attn
  us* Bb  = (us*)(ws + TB);       // vt
  us* wqb = (us*)(ws + 3 * TB);   // (2*TB gap kept for layout stability)
  us* wkb = wqb + (size_t)1024 * 1024;
  us* wvb = wkb + (size_t)1024 * 1024;
  us* wob = wvb + (size_t)1024 * 1024;
  float* part  = (float*)(wob + (size_t)1024 * 1024);     // 256*4096 fp32
  float* zpart = part + (size_t)256 * 4096;               // 256*64
  float* z     = zpart + 256 * 64;                        // 4096
  us* kvb      = (us*)(z + 4096);                         // 64*4096 bf16

  // weights -> bf16 (single launch)
  conv_w4<<<2048, 256, 0, stream>>>(wq, wk, wv, wo, wqb, wkb, wvb, wob);

  // K projection (fused fp32 read)
  proj_gemm<1><<<256, 512, 0, stream>>>((const void*)keys, wkb, bk, (void*)A);
  // V projection
  proj_gemm<2><<<256, 512, 0, stream>>>((const void*)values, wvb, bv, (void*)Bb);
  // kv + z
  kv_stage1<<<256, 256, 0, stream>>>(A, Bb, part, zpart);
  kv_stage2<<<64, 256, 0, stream>>>(part, zpart, kvb, z);
  // Q projection (kt dead; write q bf16 into A)
  proj_gemm<0><<<256, 512, 0, stream>>>((const void*)queries, wqb, bq, (void*)A);
  // attention (in place over q)
  attn_kernel<<<1024, 256, 0, stream>>>(A, kvb, z, A);
  // output projection (X = attn bf16)
  proj_gemm<3><<<256, 512, 0, stream>>>((const void*)A, wob, bo, d_out);
}

// Round 6
// 435.111 us; speedup vs baseline: 1.0204x; 1.0204x over previous
//
#include <hip/hip_runtime.h>

#define EPS 1e-6f

typedef __attribute__((ext_vector_type(8))) __bf16 bf16x8;
typedef __attribute__((ext_vector_type(4))) float f32x4;
typedef __attribute__((ext_vector_type(4))) unsigned short us4v;
typedef __attribute__((ext_vector_type(8))) unsigned short us8v;
typedef unsigned short us;

__device__ inline us f2bf(float f) {
  unsigned int u = __builtin_bit_cast(unsigned int, f);
  unsigned int r = (u + 0x7fffu + ((u >> 16) & 1u)) >> 16;
  return (us)r;
}
__device__ inline float bf2f(us s) {
  unsigned int u = ((unsigned int)s) << 16;
  return __builtin_bit_cast(float, u);
}

__device__ inline void gl_lds16(const us* g, us* l) {
  __builtin_amdgcn_global_load_lds(
      (const __attribute__((address_space(1))) unsigned int*)g,
      (__attribute__((address_space(3))) unsigned int*)l, 16, 0, 0);
}

// ---------------------------------------------------------------------------
// fp32 -> bf16 convert (RNE), n elements (multiple of 2048). grid = n/2048.
// ---------------------------------------------------------------------------
__global__ __launch_bounds__(256) void conv_bf16(const float* __restrict__ s,
                                                 us* __restrict__ d) {
  int idx = blockIdx.x * 256 + threadIdx.x;
  size_t base = (size_t)idx * 8;
  float4 a = *(const float4*)(s + base);
  float4 b = *(const float4*)(s + base + 4);
  us8v o;
  o[0] = f2bf(a.x); o[1] = f2bf(a.y); o[2] = f2bf(a.z); o[3] = f2bf(a.w);
  o[4] = f2bf(b.x); o[5] = f2bf(b.y); o[6] = f2bf(b.z); o[7] = f2bf(b.w);
  *(us8v*)(d + base) = o;
}

// weights fp32 -> bf16 (all four in one launch). grid 2048: bid>>9 = matrix.
__global__ __launch_bounds__(256) void conv_w4(const float* __restrict__ wq,
                                               const float* __restrict__ wk,
                                               const float* __restrict__ wv,
                                               const float* __restrict__ wo,
                                               us* __restrict__ dq,
                                               us* __restrict__ dk,
                                               us* __restrict__ dv,
                                               us* __restrict__ dwo) {
  int bid = blockIdx.x;
  int msel = bid >> 9, lb = bid & 511;
  const float* s = (msel == 0) ? wq : (msel == 1) ? wk : (msel == 2) ? wv : wo;
  us* d = (msel == 0) ? dq : (msel == 1) ? dk : (msel == 2) ? dv : dwo;
  int idx = lb * 256 + threadIdx.x;
  size_t base = (size_t)idx * 8;
  float4 a = *(const float4*)(s + base);
  float4 b = *(const float4*)(s + base + 4);
  us8v o;
  o[0] = f2bf(a.x); o[1] = f2bf(a.y); o[2] = f2bf(a.z); o[3] = f2bf(a.w);
  o[4] = f2bf(b.x); o[5] = f2bf(b.y); o[6] = f2bf(b.z); o[7] = f2bf(b.w);
  *(us8v*)(d + base) = o;
}

// ---------------------------------------------------------------------------
// Projection GEMM — EXACT round-3 version (best measured: ~52 us each).
// 8-phase counted-vmcnt, BM=BN=256, BK=64, 512 thr / 8 waves, gl_lds staging
// both operands, XOR-swizzled LDS, XCD-bijective block swizzle.
// MODE 0: phi (elu+1), bf16 row-major      MODE 1: phi, bf16 per-head kt
// MODE 2: id, bf16 per-head vt             MODE 3: id, fp32 row-major
// ---------------------------------------------------------------------------
template <int MODE>
__global__ __launch_bounds__(512, 2) void proj_gemm(const us* __restrict__ X,
                                                    const us* __restrict__ W,
                                                    const float* __restrict__ bias,
                                                    void* __restrict__ Yv) {
  __shared__ alignas(16) us As[2][256 * 64];
  __shared__ alignas(16) us Bs[2][256 * 64];

  const int t = threadIdx.x;
  const int wave = t >> 6, lane = t & 63;
  const int q4 = lane >> 4, l16 = lane & 15;
  const int wm = wave >> 2, wn = wave & 3;   // 2(M) x 4(N) wave grid
  const int bid = blockIdx.x;
  const int rowg = (bid & 7) * 8 + (bid >> 5);  // 0..63
  const int colg = (bid >> 3) & 3;              // 0..3
  const int rowBase = rowg << 8;
  const int colBase = colg << 8;

  // staging source (pre-swizzled granule); dest is linear (HW adds lane*16B)
  const int tr = t >> 3;
  const int gsw = ((t & 7) ^ (tr & 7)) * 8;
  const us* Xg = X + (size_t)(rowBase + tr) * 1024 + gsw;
  const us* Wg = W + (size_t)(colBase + tr) * 1024 + gsw;

  // read-side swizzled granule offsets (us), per k-slice ks=0/1
  const int gx0 = ((0 | q4) ^ (l16 & 7)) * 8;
  const int gx1 = ((4 | q4) ^ (l16 & 7)) * 8;
  const int arow_off = (wm * 128 + l16) * 64;
  const int brow_off = (wn * 64 + l16) * 64;

  f32x4 acc[8][4];
#pragma unroll
  for (int i = 0; i < 8; i++)
#pragma unroll
    for (int j = 0; j < 4; j++) acc[i][j] = (f32x4){0.f, 0.f, 0.f, 0.f};

#define STAGE_A(kt, h)                                                      \
  {                                                                         \
    us* d_ = &As[(kt) & 1][((h) * 128 + wave * 8) * 64];                    \
    const us* s_ = Xg + (size_t)((h) * 128) * 1024 + (kt) * 64;             \
    gl_lds16(s_, d_);                                                       \
    gl_lds16(s_ + (size_t)64 * 1024, d_ + 64 * 64);                         \
  }
#define STAGE_B(kt, h)                                                      \
  {                                                                         \
    us* d_ = &Bs[(kt) & 1][((h) * 128 + wave * 8) * 64];                    \
    const us* s_ = Wg + (size_t)((h) * 128) * 1024 + (kt) * 64;             \
    gl_lds16(s_, d_);                                                       \
    gl_lds16(s_ + (size_t)64 * 1024, d_ + 64 * 64);                         \
  }
#define PH_SYNC_PRE()                                                       \
  asm volatile("s_barrier" ::: "memory");                                   \
  asm volatile("s_waitcnt lgkmcnt(0)" ::: "memory");                        \
  __builtin_amdgcn_sched_barrier(0);                                        \
  __builtin_amdgcn_s_setprio(1);
#define PH_SYNC_POST()                                                      \
  __builtin_amdgcn_s_setprio(0);                                           \
  asm volatile("s_barrier" ::: "memory");
#define MFMA16(J, AF)                                                       \
  _Pragma("unroll") for (int s_i = 0; s_i < 2; ++s_i)                       \
  _Pragma("unroll") for (int ks = 0; ks < 2; ++ks)                          \
  _Pragma("unroll") for (int ni = 0; ni < 4; ++ni)                          \
    acc[2 * (J) + s_i][ni] = __builtin_amdgcn_mfma_f32_16x16x32_bf16(       \
        AF[s_i][ks], bfv[ni][ks], acc[2 * (J) + s_i][ni], 0, 0, 0);

  // prologue: B(0), A(0), B(1); allow B(1) in flight
  STAGE_B(0, 0); STAGE_B(0, 1);
  STAGE_A(0, 0); STAGE_A(0, 1);
  STAGE_B(1, 0); STAGE_B(1, 1);
  asm volatile("s_waitcnt vmcnt(4)" ::: "memory");
  asm volatile("s_barrier" ::: "memory");

#pragma unroll 2
  for (int m = 0; m < 16; ++m) {
    const int b = m & 1;
    const us* Ar = &As[b][arow_off];
    const us* Br = &Bs[b][brow_off];
    bf16x8 bfv[4][2];

    // ---- phase 0: B-all + A-pair0 ; stage A0(m+1) ----
    {
      bf16x8 af[2][2];
#pragma unroll
      for (int s_i = 0; s_i < 2; ++s_i) {
        af[s_i][0] = *(const bf16x8*)(Ar + (0 + s_i) * 1024 + gx0);
        af[s_i][1] = *(const bf16x8*)(Ar + (0 + s_i) * 1024 + gx1);
      }
#pragma unroll
      for (int ni = 0; ni < 4; ++ni) {
        bfv[ni][0] = *(const bf16x8*)(Br + ni * 1024 + gx0);
        bfv[ni][1] = *(const bf16x8*)(Br + ni * 1024 + gx1);
      }
      if (m < 15) STAGE_A(m + 1, 0);
      PH_SYNC_PRE();
      MFMA16(0, af);
      PH_SYNC_POST();
    }
    // ---- phase 1: A-pair1 ; stage A1(m+1) ----
    {
      bf16x8 af[2][2];
#pragma unroll
      for (int s_i = 0; s_i < 2; ++s_i) {
        af[s_i][0] = *(const bf16x8*)(Ar + (2 + s_i) * 1024 + gx0);
        af[s_i][1] = *(const bf16x8*)(Ar + (2 + s_i) * 1024 + gx1);
      }
      if (m < 15) STAGE_A(m + 1, 1);
      PH_SYNC_PRE();
      MFMA16(1, af);
      PH_SYNC_POST();
    }
    // ---- phase 2: A-pair2 ; stage B0(m+2) ----
    {
      bf16x8 af[2][2];
#pragma unroll
      for (int s_i = 0; s_i < 2; ++s_i) {
        af[s_i][0] = *(const bf16x8*)(Ar + (4 + s_i) * 1024 + gx0);
        af[s_i][1] = *(const bf16x8*)(Ar + (4 + s_i) * 1024 + gx1);
      }
      if (m < 14) STAGE_B(m + 2, 0);
      PH_SYNC_PRE();
      MFMA16(2, af);
      PH_SYNC_POST();
    }
    // ---- phase 3: A-pair3 ; stage B1(m+2) ; vmcnt checkpoint ----
    {
      bf16x8 af[2][2];
#pragma unroll
      for (int s_i = 0; s_i < 2; ++s_i) {
        af[s_i][0] = *(const bf16x8*)(Ar + (6 + s_i) * 1024 + gx0);
        af[s_i][1] = *(const bf16x8*)(Ar + (6 + s_i) * 1024 + gx1);
      }
      if (m < 14) STAGE_B(m + 2, 1);
      asm volatile("s_barrier" ::: "memory");
      asm volatile("s_waitcnt lgkmcnt(0)" ::: "memory");
      __builtin_amdgcn_sched_barrier(0);
      __builtin_amdgcn_s_setprio(1);
      MFMA16(3, af);
      __builtin_amdgcn_s_setprio(0);
      if (m < 14)
        asm volatile("s_waitcnt vmcnt(4)" ::: "memory");
      else
        asm volatile("s_waitcnt vmcnt(0)" ::: "memory");
      asm volatile("s_barrier" ::: "memory");
    }
  }
#undef STAGE_A
#undef STAGE_B
#undef PH_SYNC_PRE
#undef PH_SYNC_POST
#undef MFMA16

  // epilogue
#pragma unroll
  for (int j = 0; j < 4; j++) {
    int col = colBase + wn * 64 + j * 16 + l16;
    float bv = bias[col];
#pragma unroll
    for (int i = 0; i < 8; i++) {
      int row0 = rowBase + wm * 128 + i * 16 + q4 * 4;
      if (MODE == 1 || MODE == 2) {
        int bb = row0 >> 12, m0 = row0 & 4095;
        int h = col >> 6, dd = col & 63;
        us4v pk;
#pragma unroll
        for (int r = 0; r < 4; r++) {
          float y = acc[i][j][r] + bv;
          if (MODE == 1) y = (y > 0.f) ? (y + 1.f) : __expf(y);
          pk[r] = f2bf(y);
        }
        *(us4v*)&((us*)Yv)[(((size_t)((bb * 16 + h) * 64 + dd)) << 12) + m0] = pk;
      } else {
#pragma unroll
        for (int r = 0; r < 4; r++) {
          float y = acc[i][j][r] + bv;
          if (MODE == 0) {
            y = (y > 0.f) ? (y + 1.f) : __expf(y);
            ((us*)Yv)[(size_t)(row0 + r) * 1024 + col] = f2bf(y);
          } else {
            ((float*)Yv)[(size_t)(row0 + r) * 1024 + col] = y;
          }
        }
      }
    }
  }
}

// ---------------------------------------------------------------------------
// kv stage 1 v2: partial kv_t[e][d] = sum_m vt[e][m]*kt[d][m] over a 512-m
// slab + z-partials. 512 blocks (bh x 8 splits) -> 2 blocks/CU (LDS 68 KB),
// 4 waves x 128 m each, explicit 2-deep register double-buffered prefetch
// (static buffer names). Addresses/MFMA/reduction identical to v1; only the
// split bookkeeping and load pipelining changed.
// ---------------------------------------------------------------------------
__global__ __launch_bounds__(256) void kv_stage1(const us* __restrict__ kt,
                                                 const us* __restrict__ vt,
                                                 float* __restrict__ part,
                                                 float* __restrict__ zpart) {
  __shared__ float red[4][4096];
  __shared__ float zred[4][64][4];

  const int blk = blockIdx.x;            // 512
  const int bh = blk & 63, split = blk >> 6;
  const int t = threadIdx.x;
  const int w = t >> 6, lane = t & 63;
  const int q4 = lane >> 4, l16 = lane & 15;
  const us* ktb = kt + (size_t)bh * 64 * 4096;
  const us* vtb = vt + (size_t)bh * 64 * 4096;
  const int mbeg = split * 512 + w * 128;

  f32x4 acc[4][4];
#pragma unroll
  for (int i = 0; i < 4; i++)
#pragma unroll
    for (int j = 0; j < 4; j++) acc[i][j] = (f32x4){0.f, 0.f, 0.f, 0.f};
  float zacc[4] = {0.f, 0.f, 0.f, 0.f};

  us8v ka[4], va[4], kb[4], vb[4];
#define LOADF(K, V, m0)                                                       \
  _Pragma("unroll") for (int i = 0; i < 4; ++i) {                             \
    V[i] = *(const us8v*)&vtb[(size_t)(i * 16 + l16) * 4096 + (m0) + q4 * 8]; \
    K[i] = *(const us8v*)&ktb[(size_t)(i * 16 + l16) * 4096 + (m0) + q4 * 8]; \
  }
#define STEPF(K, V)                                                           \
  {                                                                           \
    bf16x8 af[4], bfr[4];                                                     \
    _Pragma("unroll") for (int j = 0; j < 4; ++j) {                           \
      bfr[j] = __builtin_bit_cast(bf16x8, K[j]);                              \
      _Pragma("unroll") for (int e = 0; e < 8; ++e) zacc[j] += bf2f(K[j][e]); \
    }                                                                         \
    _Pragma("unroll") for (int i = 0; i < 4; ++i)                             \
      af[i] = __builtin_bit_cast(bf16x8, V[i]);                               \
    _Pragma("unroll") for (int i = 0; i < 4; ++i)                             \
      _Pragma("unroll") for (int j = 0; j < 4; ++j)                           \
        acc[i][j] = __builtin_amdgcn_mfma_f32_16x16x32_bf16(                  \
            af[i], bfr[j], acc[i][j], 0, 0, 0);                               \
  }

  LOADF(ka, va, mbeg);
  LOADF(kb, vb, mbeg + 32);
  STEPF(ka, va);
  LOADF(ka, va, mbeg + 64);
  STEPF(kb, vb);
  LOADF(kb, vb, mbeg + 96);
  STEPF(ka, va);
  STEPF(kb, vb);
#undef LOADF
#undef STEPF

#pragma unroll
  for (int i = 0; i < 4; i++)
#pragma unroll
    for (int j = 0; j < 4; j++)
#pragma unroll
      for (int r = 0; r < 4; r++)
        red[w][(i * 16 + q4 * 4 + r) * 64 + j * 16 + l16] = acc[i][j][r];
#pragma unroll
  for (int j = 0; j < 4; j++) zred[w][j * 16 + l16][q4] = zacc[j];
  __syncthreads();

  float* pb = part + (size_t)blk * 4096;
#pragma unroll
  for (int i = 0; i < 16; i++) {
    int idx = t + 256 * i;
    pb[idx] = red[0][idx] + red[1][idx] + red[2][idx] + red[3][idx];
  }
  if (t < 64) {
    float s = 0.f;
#pragma unroll
    for (int w2 = 0; w2 < 4; w2++)
#pragma unroll
      for (int q = 0; q < 4; q++) s += zred[w2][t][q];
    zpart[blk * 64 + t] = s;
  }
}

// stage 2: reduce the 8 split-partials -> kv bf16 + z fp32. 64 blocks.
__global__ __launch_bounds__(256) void kv_stage2(const float* __restrict__ part,
                                                 const float* __restrict__ zpart,
                                                 us* __restrict__ kvb,
                                                 float* __restrict__ z) {
  const int bh = blockIdx.x;
  const int t = threadIdx.x;
  const float* p0 = part + (size_t)bh * 4096;          // stride 64*4096 per split
#pragma unroll
  for (int i = 0; i < 16; i++) {
    int idx = t + 256 * i;
    float s = 0.f;
#pragma unroll
    for (int sp = 0; sp < 8; sp++) s += p0[(size_t)sp * 262144 + idx];
    kvb[(size_t)bh * 4096 + idx] = f2bf(s);
  }
  if (t < 64) {
    const float* zp = zpart + bh * 64;                  // stride 64*64 per split
    float s = 0.f;
#pragma unroll
    for (int sp = 0; sp < 8; sp++) s += zp[sp * 4096 + t];
    z[bh * 64 + t] = s;
  }
}

// ---------------------------------------------------------------------------
// attn[b][n][h*64+e] = (sum_d q[n][d] kv[d][e]) / (q[n]·z + eps), bf16,
// written IN PLACE over q (each block reads exactly the region it writes).
// ---------------------------------------------------------------------------
__global__ __launch_bounds__(256) void attn_kernel(const us* __restrict__ q,
                                                   const us* __restrict__ kvb,
                                                   const float* __restrict__ z,
                                                   us* __restrict__ attn) {
  __shared__ alignas(16) us kvs[64 * 72];
  __shared__ float zs[64];
  __shared__ float invden[256];

  const int bid = blockIdx.x;
  const int bh = bid >> 4, nc = bid & 15;
  const int b = bh >> 4, h = bh & 15;
  const int n0 = nc * 256;
  const int t = threadIdx.x;
  const int wave = t >> 6, lane = t & 63;
  const int q4 = lane >> 4, l16 = lane & 15;

#pragma unroll
  for (int i = 0; i < 2; i++) {
    int chunk = t + 256 * i;          // 0..511
    int e = chunk >> 3, d8 = chunk & 7;
    us8v vv = *(const us8v*)&kvb[(size_t)bh * 4096 + chunk * 8];
    *(us8v*)&kvs[e * 72 + d8 * 8] = vv;
  }
  if (t < 64) zs[t] = z[bh * 64 + t];
  __syncthreads();

  {
    const us* qrow = q + ((size_t)(b * 4096 + n0 + t)) * 1024 + h * 64;
    float s = 0.f;
#pragma unroll
    for (int d0 = 0; d0 < 64; d0 += 8) {
      us8v v = *(const us8v*)(qrow + d0);
#pragma unroll
      for (int j = 0; j < 8; j++) s += bf2f(v[j]) * zs[d0 + j];
    }
    invden[t] = 1.0f / (s + EPS);
  }
  __syncthreads();

  f32x4 acc[4][4];
#pragma unroll
  for (int i = 0; i < 4; i++)
#pragma unroll
    for (int j = 0; j < 4; j++) acc[i][j] = (f32x4){0.f, 0.f, 0.f, 0.f};

  const us* qb = q + ((size_t)(b * 4096 + n0 + wave * 64)) * 1024 + h * 64;
#pragma unroll
  for (int ks = 0; ks < 2; ks++) {
    bf16x8 af[4], bfr[4];
#pragma unroll
    for (int i = 0; i < 4; i++)
      af[i] = *(const bf16x8*)(qb + (size_t)(i * 16 + l16) * 1024 + ks * 32 + q4 * 8);
#pragma unroll
    for (int j = 0; j < 4; j++)
      bfr[j] = *(const bf16x8*)&kvs[(j * 16 + l16) * 72 + ks * 32 + q4 * 8];
#pragma unroll
    for (int i = 0; i < 4; i++)
#pragma unroll
      for (int j = 0; j < 4; j++)
        acc[i][j] = __builtin_amdgcn_mfma_f32_16x16x32_bf16(af[i], bfr[j], acc[i][j], 0, 0, 0);
  }

  us* ab = attn + ((size_t)(b * 4096 + n0 + wave * 64)) * 1024 + h * 64;
#pragma unroll
  for (int i = 0; i < 4; i++)
#pragma unroll
    for (int j = 0; j < 4; j++)
#pragma unroll
      for (int r = 0; r < 4; r++) {
        int rowl = i * 16 + q4 * 4 + r;
        int nl = wave * 64 + rowl;
        int e = j * 16 + l16;
        ab[(size_t)rowl * 1024 + e] = f2bf(acc[i][j][r] * invden[nl]);
      }
}

// ---------------------------------------------------------------------------
extern "C" void kernel_launch(void* const* d_in, const int* in_sizes, int n_in,
                              void* d_out, int out_size, void* d_ws, size_t ws_size,
                              hipStream_t stream) {
  const float* queries = (const float*)d_in[0];
  const float* keys    = (const float*)d_in[1];
  const float* values  = (const float*)d_in[2];
  const float* wq = (const float*)d_in[3];
  const float* bq = (const float*)d_in[4];
  const float* wk = (const float*)d_in[5];
  const float* bk = (const float*)d_in[6];
  const float* wv = (const float*)d_in[7];
  const float* bv = (const float*)d_in[8];
  const float* wo = (const float*)d_in[9];
  const float* bo = (const float*)d_in[10];

  char* ws = (char*)d_ws;
  const size_t TB = (size_t)16384 * 1024 * 2;   // 33.55 MB per big bf16 buffer
  us* A   = (us*)(ws);            // kt, later q/attn
  us* Bb  = (us*)(ws + TB);       // vt, later queries-bf16
  us* Xb  = (us*)(ws + 2 * TB);   // keys/values bf16 scratch; later part/zpart
  us* wqb = (us*)(ws + 3 * TB);
  us* wkb = wqb + (size_t)1024 * 1024;
  us* wvb = wkb + (size_t)1024 * 1024;
  us* wob = wvb + (size_t)1024 * 1024;
  float* z   = (float*)(wob + (size_t)1024 * 1024);       // 4096 fp32
  us* kvb    = (us*)(z + 4096);                           // 64*4096 bf16
  // part/zpart alias Xb (dead after proj<2> has consumed values-bf16):
  float* part  = (float*)Xb;                              // 512*4096 fp32 (8.4MB)
  float* zpart = part + (size_t)512 * 4096;               // 512*64 fp32

  const int GRID_IN = 16384 * 1024 / 2048;   // 8192

  // weights -> bf16 (single launch)
  conv_w4<<<2048, 256, 0, stream>>>(wq, wk, wv, wo, wqb, wkb, wvb, wob);

  // K projection
  conv_bf16<<<GRID_IN, 256, 0, stream>>>(keys, Xb);
  proj_gemm<1><<<256, 512, 0, stream>>>(Xb, wkb, bk, (void*)A);
  // V projection
  conv_bf16<<<GRID_IN, 256, 0, stream>>>(values, Xb);
  proj_gemm<2><<<256, 512, 0, stream>>>(Xb, wvb, bv, (void*)Bb);
  // kv + z (part/zpart now alias the dead Xb slab)
  kv_stage1<<<512, 256, 0, stream>>>(A, Bb, part, zpart);
  kv_stage2<<<64, 256, 0, stream>>>(part, zpart, kvb, z);
  // Q projection (kt/vt dead; reuse buffers)
  conv_bf16<<<GRID_IN, 256, 0, stream>>>(queries, Bb);
  proj_gemm<0><<<256, 512, 0, stream>>>(Bb, wqb, bq, (void*)A);
  // attention (in place over q)
  attn_kernel<<<1024, 256, 0, stream>>>(A, kvb, z, A);
  // output projection
  proj_gemm<3><<<256, 512, 0, stream>>>(A, wob, bo, d_out);
}

// Round 7
// 429.296 us; speedup vs baseline: 1.0342x; 1.0135x over previous
//
#include <hip/hip_runtime.h>

#define EPS 1e-6f

typedef __attribute__((ext_vector_type(8))) __bf16 bf16x8;
typedef __attribute__((ext_vector_type(4))) float f32x4;
typedef __attribute__((ext_vector_type(4))) unsigned short us4v;
typedef __attribute__((ext_vector_type(8))) unsigned short us8v;
typedef unsigned short us;

__device__ inline us f2bf(float f) {
  unsigned int u = __builtin_bit_cast(unsigned int, f);
  unsigned int r = (u + 0x7fffu + ((u >> 16) & 1u)) >> 16;
  return (us)r;
}
__device__ inline float bf2f(us s) {
  unsigned int u = ((unsigned int)s) << 16;
  return __builtin_bit_cast(float, u);
}

__device__ inline void gl_lds16(const us* g, us* l) {
  __builtin_amdgcn_global_load_lds(
      (const __attribute__((address_space(1))) unsigned int*)g,
      (__attribute__((address_space(3))) unsigned int*)l, 16, 0, 0);
}

// epilogue-transpose LDS swizzle: inject col bits into row bits 2-5 so that
// (a) writer (lanes vary lc by 1, lr fixed)        -> <=4-way
// (b) kt-reader (lc fixed, lr = lane*4)            -> conflict-free
// (c) row-reader (lr fixed, lc = lane*4+d)         -> <=4-way
#define EMASK(lc) (((((lc) & 15) ^ (((lc) >> 4) & 3)) << 2))

// ---------------------------------------------------------------------------
// fp32 -> bf16 convert (RNE), n elements (multiple of 2048). grid = n/2048.
// ---------------------------------------------------------------------------
__global__ __launch_bounds__(256) void conv_bf16(const float* __restrict__ s,
                                                 us* __restrict__ d) {
  int idx = blockIdx.x * 256 + threadIdx.x;
  size_t base = (size_t)idx * 8;
  float4 a = *(const float4*)(s + base);
  float4 b = *(const float4*)(s + base + 4);
  us8v o;
  o[0] = f2bf(a.x); o[1] = f2bf(a.y); o[2] = f2bf(a.z); o[3] = f2bf(a.w);
  o[4] = f2bf(b.x); o[5] = f2bf(b.y); o[6] = f2bf(b.z); o[7] = f2bf(b.w);
  *(us8v*)(d + base) = o;
}

// weights fp32 -> bf16 (all four in one launch). grid 2048: bid>>9 = matrix.
__global__ __launch_bounds__(256) void conv_w4(const float* __restrict__ wq,
                                               const float* __restrict__ wk,
                                               const float* __restrict__ wv,
                                               const float* __restrict__ wo,
                                               us* __restrict__ dq,
                                               us* __restrict__ dk,
                                               us* __restrict__ dv,
                                               us* __restrict__ dwo) {
  int bid = blockIdx.x;
  int msel = bid >> 9, lb = bid & 511;
  const float* s = (msel == 0) ? wq : (msel == 1) ? wk : (msel == 2) ? wv : wo;
  us* d = (msel == 0) ? dq : (msel == 1) ? dk : (msel == 2) ? dv : dwo;
  int idx = lb * 256 + threadIdx.x;
  size_t base = (size_t)idx * 8;
  float4 a = *(const float4*)(s + base);
  float4 b = *(const float4*)(s + base + 4);
  us8v o;
  o[0] = f2bf(a.x); o[1] = f2bf(a.y); o[2] = f2bf(a.z); o[3] = f2bf(a.w);
  o[4] = f2bf(b.x); o[5] = f2bf(b.y); o[6] = f2bf(b.z); o[7] = f2bf(b.w);
  *(us8v*)(d + base) = o;
}

// ---------------------------------------------------------------------------
// Projection GEMM — round-3 main loop (best measured) + LDS-transposed,
// fully-coalesced epilogue for bf16 outputs (kills the 2.4x HBM write
// amplification seen as WRITE_SIZE 81.5MB vs 33.5MB logical).
// 8-phase counted-vmcnt, BM=BN=256, BK=64, 512 thr / 8 waves, gl_lds staging
// both operands, XOR-swizzled LDS, XCD-bijective block swizzle.
// MODE 0: phi (elu+1), bf16 row-major      MODE 1: phi, bf16 per-head kt
// MODE 2: id, bf16 per-head vt             MODE 3: id, fp32 row-major
// ---------------------------------------------------------------------------
template <int MODE>
__global__ __launch_bounds__(512, 2) void proj_gemm(const us* __restrict__ X,
                                                    const us* __restrict__ W,
                                                    const float* __restrict__ bias,
                                                    void* __restrict__ Yv) {
  // one 128KB arena: As = SH[0..32K), Bs = SH[32K..64K) (us units);
  // after the K-loop the whole arena is reused as the 256x256 us tile T.
  __shared__ alignas(16) us SH[65536];
  us* As0 = SH;
  us* As1 = SH + 16384;
  us* Bs0 = SH + 32768;
  us* Bs1 = SH + 49152;

  const int t = threadIdx.x;
  const int wave = t >> 6, lane = t & 63;
  const int q4 = lane >> 4, l16 = lane & 15;
  const int wm = wave >> 2, wn = wave & 3;   // 2(M) x 4(N) wave grid
  const int bid = blockIdx.x;
  const int rowg = (bid & 7) * 8 + (bid >> 5);  // 0..63
  const int colg = (bid >> 3) & 3;              // 0..3
  const int rowBase = rowg << 8;
  const int colBase = colg << 8;

  // staging source (pre-swizzled granule); dest is linear (HW adds lane*16B)
  const int tr = t >> 3;
  const int gsw = ((t & 7) ^ (tr & 7)) * 8;
  const us* Xg = X + (size_t)(rowBase + tr) * 1024 + gsw;
  const us* Wg = W + (size_t)(colBase + tr) * 1024 + gsw;

  // read-side swizzled granule offsets (us), per k-slice ks=0/1
  const int gx0 = ((0 | q4) ^ (l16 & 7)) * 8;
  const int gx1 = ((4 | q4) ^ (l16 & 7)) * 8;
  const int arow_off = (wm * 128 + l16) * 64;
  const int brow_off = (wn * 64 + l16) * 64;

  f32x4 acc[8][4];
#pragma unroll
  for (int i = 0; i < 8; i++)
#pragma unroll
    for (int j = 0; j < 4; j++) acc[i][j] = (f32x4){0.f, 0.f, 0.f, 0.f};

#define STAGE_A(kt, h)                                                      \
  {                                                                         \
    us* d_ = ((kt) & 1 ? As1 : As0) + ((h) * 128 + wave * 8) * 64;          \
    const us* s_ = Xg + (size_t)((h) * 128) * 1024 + (kt) * 64;             \
    gl_lds16(s_, d_);                                                       \
    gl_lds16(s_ + (size_t)64 * 1024, d_ + 64 * 64);                         \
  }
#define STAGE_B(kt, h)                                                      \
  {                                                                         \
    us* d_ = ((kt) & 1 ? Bs1 : Bs0) + ((h) * 128 + wave * 8) * 64;          \
    const us* s_ = Wg + (size_t)((h) * 128) * 1024 + (kt) * 64;             \
    gl_lds16(s_, d_);                                                       \
    gl_lds16(s_ + (size_t)64 * 1024, d_ + 64 * 64);                         \
  }
#define PH_SYNC_PRE()                                                       \
  asm volatile("s_barrier" ::: "memory");                                   \
  asm volatile("s_waitcnt lgkmcnt(0)" ::: "memory");                        \
  __builtin_amdgcn_sched_barrier(0);                                        \
  __builtin_amdgcn_s_setprio(1);
#define PH_SYNC_POST()                                                      \
  __builtin_amdgcn_s_setprio(0);                                           \
  asm volatile("s_barrier" ::: "memory");
#define MFMA16(J, AF)                                                       \
  _Pragma("unroll") for (int s_i = 0; s_i < 2; ++s_i)                       \
  _Pragma("unroll") for (int ks = 0; ks < 2; ++ks)                          \
  _Pragma("unroll") for (int ni = 0; ni < 4; ++ni)                          \
    acc[2 * (J) + s_i][ni] = __builtin_amdgcn_mfma_f32_16x16x32_bf16(       \
        AF[s_i][ks], bfv[ni][ks], acc[2 * (J) + s_i][ni], 0, 0, 0);

  // prologue: B(0), A(0), B(1); allow B(1) in flight
  STAGE_B(0, 0); STAGE_B(0, 1);
  STAGE_A(0, 0); STAGE_A(0, 1);
  STAGE_B(1, 0); STAGE_B(1, 1);
  asm volatile("s_waitcnt vmcnt(4)" ::: "memory");
  asm volatile("s_barrier" ::: "memory");

#pragma unroll 2
  for (int m = 0; m < 16; ++m) {
    const int b = m & 1;
    const us* Ar = (b ? As1 : As0) + arow_off;
    const us* Br = (b ? Bs1 : Bs0) + brow_off;
    bf16x8 bfv[4][2];

    // ---- phase 0: B-all + A-pair0 ; stage A0(m+1) ----
    {
      bf16x8 af[2][2];
#pragma unroll
      for (int s_i = 0; s_i < 2; ++s_i) {
        af[s_i][0] = *(const bf16x8*)(Ar + (0 + s_i) * 1024 + gx0);
        af[s_i][1] = *(const bf16x8*)(Ar + (0 + s_i) * 1024 + gx1);
      }
#pragma unroll
      for (int ni = 0; ni < 4; ++ni) {
        bfv[ni][0] = *(const bf16x8*)(Br + ni * 1024 + gx0);
        bfv[ni][1] = *(const bf16x8*)(Br + ni * 1024 + gx1);
      }
      if (m < 15) STAGE_A(m + 1, 0);
      PH_SYNC_PRE();
      MFMA16(0, af);
      PH_SYNC_POST();
    }
    // ---- phase 1: A-pair1 ; stage A1(m+1) ----
    {
      bf16x8 af[2][2];
#pragma unroll
      for (int s_i = 0; s_i < 2; ++s_i) {
        af[s_i][0] = *(const bf16x8*)(Ar + (2 + s_i) * 1024 + gx0);
        af[s_i][1] = *(const bf16x8*)(Ar + (2 + s_i) * 1024 + gx1);
      }
      if (m < 15) STAGE_A(m + 1, 1);
      PH_SYNC_PRE();
      MFMA16(1, af);
      PH_SYNC_POST();
    }
    // ---- phase 2: A-pair2 ; stage B0(m+2) ----
    {
      bf16x8 af[2][2];
#pragma unroll
      for (int s_i = 0; s_i < 2; ++s_i) {
        af[s_i][0] = *(const bf16x8*)(Ar + (4 + s_i) * 1024 + gx0);
        af[s_i][1] = *(const bf16x8*)(Ar + (4 + s_i) * 1024 + gx1);
      }
      if (m < 14) STAGE_B(m + 2, 0);
      PH_SYNC_PRE();
      MFMA16(2, af);
      PH_SYNC_POST();
    }
    // ---- phase 3: A-pair3 ; stage B1(m+2) ; vmcnt checkpoint ----
    {
      bf16x8 af[2][2];
#pragma unroll
      for (int s_i = 0; s_i < 2; ++s_i) {
        af[s_i][0] = *(const bf16x8*)(Ar + (6 + s_i) * 1024 + gx0);
        af[s_i][1] = *(const bf16x8*)(Ar + (6 + s_i) * 1024 + gx1);
      }
      if (m < 14) STAGE_B(m + 2, 1);
      asm volatile("s_barrier" ::: "memory");
      asm volatile("s_waitcnt lgkmcnt(0)" ::: "memory");
      __builtin_amdgcn_sched_barrier(0);
      __builtin_amdgcn_s_setprio(1);
      MFMA16(3, af);
      __builtin_amdgcn_s_setprio(0);
      if (m < 14)
        asm volatile("s_waitcnt vmcnt(4)" ::: "memory");
      else
        asm volatile("s_waitcnt vmcnt(0)" ::: "memory");
      asm volatile("s_barrier" ::: "memory");
    }
  }
#undef STAGE_A
#undef STAGE_B
#undef PH_SYNC_PRE
#undef PH_SYNC_POST
#undef MFMA16

  // ------------------------- epilogue -------------------------
  if (MODE == 3) {
    // fp32 row-major, direct (write amplification mild for 4B elems)
#pragma unroll
    for (int j = 0; j < 4; j++) {
      int col = colBase + wn * 64 + j * 16 + l16;
      float bv = bias[col];
#pragma unroll
      for (int i = 0; i < 8; i++) {
        int row0 = rowBase + wm * 128 + i * 16 + q4 * 4;
#pragma unroll
        for (int r = 0; r < 4; r++)
          ((float*)Yv)[(size_t)(row0 + r) * 1024 + col] = acc[i][j][r] + bv;
      }
    }
  } else {
    // stage tile into T[lc][lr^EMASK(lc)] (us), then coalesced global stores.
    // main loop's final barrier already passed -> all LDS reads of As/Bs done.
    us* T = SH;  // 256x256 us = 128KB
#pragma unroll
    for (int j = 0; j < 4; j++) {
      int lc = wn * 64 + j * 16 + l16;
      float bv = bias[colBase + lc];
#pragma unroll
      for (int i = 0; i < 8; i++) {
        int lr0 = wm * 128 + i * 16 + q4 * 4;
        us4v pk;
#pragma unroll
        for (int r = 0; r < 4; r++) {
          float y = acc[i][j][r] + bv;
          if (MODE != 2) y = (y > 0.f) ? (y + 1.f) : __expf(y);
          pk[r] = f2bf(y);
        }
        *(us4v*)&T[lc * 256 + (lr0 ^ EMASK(lc))] = pk;
      }
    }
    __syncthreads();

    if (MODE == 1 || MODE == 2) {
      // kt/vt: out[((b*16+h)*64+dd)<<12 | m], per lc-row 512B contiguous.
      const int bb = rowBase >> 12, m0 = rowBase & 4095;
#pragma unroll
      for (int kk = 0; kk < 32; kk++) {
        int lc = wave + 8 * kk;
        int gcol = colBase + lc;
        int h = gcol >> 6, dd = gcol & 63;
        us4v v = *(const us4v*)&T[lc * 256 + ((lane * 4) ^ EMASK(lc))];
        *(us4v*)&((us*)Yv)[(((size_t)((bb * 16 + h) * 64 + dd)) << 12) + m0 +
                           lane * 4] = v;
      }
    } else {
      // row-major q: per lr-row 512B contiguous (gathered 4x b16 per lane).
#pragma unroll
      for (int kk = 0; kk < 32; kk++) {
        int lr = wave + 8 * kk;
        us4v v;
#pragma unroll
        for (int d = 0; d < 4; d++) {
          int lc = lane * 4 + d;
          v[d] = T[lc * 256 + (lr ^ EMASK(lc))];
        }
        *(us4v*)&((us*)Yv)[(size_t)(rowBase + lr) * 1024 + colBase +
                           lane * 4] = v;
      }
    }
  }
}

// ---------------------------------------------------------------------------
// kv stage 1 v2: partial kv_t[e][d] = sum_m vt[e][m]*kt[d][m] over a 512-m
// slab + z-partials. 512 blocks (bh x 8 splits), 4 waves x 128 m each,
// 2-deep register double-buffered prefetch (static buffer names).
// ---------------------------------------------------------------------------
__global__ __launch_bounds__(256) void kv_stage1(const us* __restrict__ kt,
                                                 const us* __restrict__ vt,
                                                 float* __restrict__ part,
                                                 float* __restrict__ zpart) {
  __shared__ float red[4][4096];
  __shared__ float zred[4][64][4];

  const int blk = blockIdx.x;            // 512
  const int bh = blk & 63, split = blk >> 6;
  const int t = threadIdx.x;
  const int w = t >> 6, lane = t & 63;
  const int q4 = lane >> 4, l16 = lane & 15;
  const us* ktb = kt + (size_t)bh * 64 * 4096;
  const us* vtb = vt + (size_t)bh * 64 * 4096;
  const int mbeg = split * 512 + w * 128;

  f32x4 acc[4][4];
#pragma unroll
  for (int i = 0; i < 4; i++)
#pragma unroll
    for (int j = 0; j < 4; j++) acc[i][j] = (f32x4){0.f, 0.f, 0.f, 0.f};
  float zacc[4] = {0.f, 0.f, 0.f, 0.f};

  us8v ka[4], va[4], kb[4], vb[4];
#define LOADF(K, V, m0)                                                       \
  _Pragma("unroll") for (int i = 0; i < 4; ++i) {                             \
    V[i] = *(const us8v*)&vtb[(size_t)(i * 16 + l16) * 4096 + (m0) + q4 * 8]; \
    K[i] = *(const us8v*)&ktb[(size_t)(i * 16 + l16) * 4096 + (m0) + q4 * 8]; \
  }
#define STEPF(K, V)                                                           \
  {                                                                           \
    bf16x8 af[4], bfr[4];                                                     \
    _Pragma("unroll") for (int j = 0; j < 4; ++j) {                           \
      bfr[j] = __builtin_bit_cast(bf16x8, K[j]);                              \
      _Pragma("unroll") for (int e = 0; e < 8; ++e) zacc[j] += bf2f(K[j][e]); \
    }                                                                         \
    _Pragma("unroll") for (int i = 0; i < 4; ++i)                             \
      af[i] = __builtin_bit_cast(bf16x8, V[i]);                               \
    _Pragma("unroll") for (int i = 0; i < 4; ++i)                             \
      _Pragma("unroll") for (int j = 0; j < 4; ++j)                           \
        acc[i][j] = __builtin_amdgcn_mfma_f32_16x16x32_bf16(                  \
            af[i], bfr[j], acc[i][j], 0, 0, 0);                               \
  }

  LOADF(ka, va, mbeg);
  LOADF(kb, vb, mbeg + 32);
  STEPF(ka, va);
  LOADF(ka, va, mbeg + 64);
  STEPF(kb, vb);
  LOADF(kb, vb, mbeg + 96);
  STEPF(ka, va);
  STEPF(kb, vb);
#undef LOADF
#undef STEPF

#pragma unroll
  for (int i = 0; i < 4; i++)
#pragma unroll
    for (int j = 0; j < 4; j++)
#pragma unroll
      for (int r = 0; r < 4; r++)
        red[w][(i * 16 + q4 * 4 + r) * 64 + j * 16 + l16] = acc[i][j][r];
#pragma unroll
  for (int j = 0; j < 4; j++) zred[w][j * 16 + l16][q4] = zacc[j];
  __syncthreads();

  float* pb = part + (size_t)blk * 4096;
#pragma unroll
  for (int i = 0; i < 16; i++) {
    int idx = t + 256 * i;
    pb[idx] = red[0][idx] + red[1][idx] + red[2][idx] + red[3][idx];
  }
  if (t < 64) {
    float s = 0.f;
#pragma unroll
    for (int w2 = 0; w2 < 4; w2++)
#pragma unroll
      for (int q = 0; q < 4; q++) s += zred[w2][t][q];
    zpart[blk * 64 + t] = s;
  }
}

// stage 2: reduce the 8 split-partials -> kv bf16 + z fp32. 64 blocks.
__global__ __launch_bounds__(256) void kv_stage2(const float* __restrict__ part,
                                                 const float* __restrict__ zpart,
                                                 us* __restrict__ kvb,
                                                 float* __restrict__ z) {
  const int bh = blockIdx.x;
  const int t = threadIdx.x;
  const float* p0 = part + (size_t)bh * 4096;
#pragma unroll
  for (int i = 0; i < 16; i++) {
    int idx = t + 256 * i;
    float s = 0.f;
#pragma unroll
    for (int sp = 0; sp < 8; sp++) s += p0[(size_t)sp * 262144 + idx];
    kvb[(size_t)bh * 4096 + idx] = f2bf(s);
  }
  if (t < 64) {
    const float* zp = zpart + bh * 64;
    float s = 0.f;
#pragma unroll
    for (int sp = 0; sp < 8; sp++) s += zp[sp * 4096 + t];
    z[bh * 64 + t] = s;
  }
}

// ---------------------------------------------------------------------------
// attn[b][n][h*64+e] = (sum_d q[n][d] kv[d][e]) / (q[n]·z + eps), bf16,
// written IN PLACE over q. Output now staged through LDS (T2 aliases kvs
// after a barrier) -> fully coalesced 128B-line stores.
// ---------------------------------------------------------------------------
__global__ __launch_bounds__(256) void attn_kernel(const us* __restrict__ q,
                                                   const us* __restrict__ kvb,
                                                   const float* __restrict__ z,
                                                   us* __restrict__ attn) {
  __shared__ alignas(16) us SH2[16384];   // kvs (first 4608 us), later T2[64][256]
  __shared__ float zs[64];
  __shared__ float invden[256];

  us* kvs = SH2;

  const int bid = blockIdx.x;
  const int bh = bid >> 4, nc = bid & 15;
  const int b = bh >> 4, h = bh & 15;
  const int n0 = nc * 256;
  const int t = threadIdx.x;
  const int wave = t >> 6, lane = t & 63;
  const int q4 = lane >> 4, l16 = lane & 15;

#pragma unroll
  for (int i = 0; i < 2; i++) {
    int chunk = t + 256 * i;          // 0..511
    int e = chunk >> 3, d8 = chunk & 7;
    us8v vv = *(const us8v*)&kvb[(size_t)bh * 4096 + chunk * 8];
    *(us8v*)&kvs[e * 72 + d8 * 8] = vv;
  }
  if (t < 64) zs[t] = z[bh * 64 + t];
  __syncthreads();

  {
    const us* qrow = q + ((size_t)(b * 4096 + n0 + t)) * 1024 + h * 64;
    float s = 0.f;
#pragma unroll
    for (int d0 = 0; d0 < 64; d0 += 8) {
      us8v v = *(const us8v*)(qrow + d0);
#pragma unroll
      for (int j = 0; j < 8; j++) s += bf2f(v[j]) * zs[d0 + j];
    }
    invden[t] = 1.0f / (s + EPS);
  }
  __syncthreads();

  f32x4 acc[4][4];
#pragma unroll
  for (int i = 0; i < 4; i++)
#pragma unroll
    for (int j = 0; j < 4; j++) acc[i][j] = (f32x4){0.f, 0.f, 0.f, 0.f};

  const us* qb = q + ((size_t)(b * 4096 + n0 + wave * 64)) * 1024 + h * 64;
#pragma unroll
  for (int ks = 0; ks < 2; ks++) {
    bf16x8 af[4], bfr[4];
#pragma unroll
    for (int i = 0; i < 4; i++)
      af[i] = *(const bf16x8*)(qb + (size_t)(i * 16 + l16) * 1024 + ks * 32 + q4 * 8);
#pragma unroll
    for (int j = 0; j < 4; j++)
      bfr[j] = *(const bf16x8*)&kvs[(j * 16 + l16) * 72 + ks * 32 + q4 * 8];
#pragma unroll
    for (int i = 0; i < 4; i++)
#pragma unroll
      for (int j = 0; j < 4; j++)
        acc[i][j] = __builtin_amdgcn_mfma_f32_16x16x32_bf16(af[i], bfr[j], acc[i][j], 0, 0, 0);
  }

  // all kvs reads done (MFMA inputs in regs) -> barrier, then reuse SH2 as T2.
  __syncthreads();
  us* T2 = SH2;   // T2[e][n] us, 64*256
#pragma unroll
  for (int i = 0; i < 4; i++)
#pragma unroll
    for (int j = 0; j < 4; j++) {
      int e = j * 16 + l16;
      int nl0 = wave * 64 + i * 16 + q4 * 4;
      us4v pk;
#pragma unroll
      for (int r = 0; r < 4; r++)
        pk[r] = f2bf(acc[i][j][r] * invden[nl0 + r]);
      *(us4v*)&T2[e * 256 + (nl0 ^ EMASK(e))] = pk;
    }
  __syncthreads();

  // coalesced out: per pass, threads cover 32 n-rows x full 128B row segment.
  us* ob = attn + ((size_t)(b * 4096 + n0)) * 1024 + h * 64;
#pragma unroll
  for (int pass = 0; pass < 8; pass++) {
    int n = pass * 32 + (t >> 3);
    int e0 = (t & 7) * 8;
    us8v v;
#pragma unroll
    for (int d = 0; d < 8; d++) {
      int e = e0 + d;
      v[d] = T2[e * 256 + (n ^ EMASK(e))];
    }
    *(us8v*)&ob[(size_t)n * 1024 + e0] = v;
  }
}

// ---------------------------------------------------------------------------
extern "C" void kernel_launch(void* const* d_in, const int* in_sizes, int n_in,
                              void* d_out, int out_size, void* d_ws, size_t ws_size,
                              hipStream_t stream) {
  const float* queries = (const float*)d_in[0];
  const float* keys    = (const float*)d_in[1];
  const float* values  = (const float*)d_in[2];
  const float* wq = (const float*)d_in[3];
  const float* bq = (const float*)d_in[4];
  const float* wk = (const float*)d_in[5];
  const float* bk = (const float*)d_in[6];
  const float* wv = (const float*)d_in[7];
  const float* bv = (const float*)d_in[8];
  const float* wo = (const float*)d_in[9];
  const float* bo = (const float*)d_in[10];

  char* ws = (char*)d_ws;
  const size_t TB = (size_t)16384 * 1024 * 2;   // 33.55 MB per big bf16 buffer
  us* A   = (us*)(ws);            // kt, later q/attn
  us* Bb  = (us*)(ws + TB);       // vt, later queries-bf16
  us* Xb  = (us*)(ws + 2 * TB);   // keys/values bf16 scratch; later part/zpart
  us* wqb = (us*)(ws + 3 * TB);
  us* wkb = wqb + (size_t)1024 * 1024;
  us* wvb = wkb + (size_t)1024 * 1024;
  us* wob = wvb + (size_t)1024 * 1024;
  float* z   = (float*)(wob + (size_t)1024 * 1024);       // 4096 fp32
  us* kvb    = (us*)(z + 4096);                           // 64*4096 bf16
  // part/zpart alias Xb (dead after proj<2> has consumed values-bf16):
  float* part  = (float*)Xb;                              // 512*4096 fp32
  float* zpart = part + (size_t)512 * 4096;               // 512*64 fp32

  const int GRID_IN = 16384 * 1024 / 2048;   // 8192

  // weights -> bf16 (single launch)
  conv_w4<<<2048, 256, 0, stream>>>(wq, wk, wv, wo, wqb, wkb, wvb, wob);

  // K projection
  conv_bf16<<<GRID_IN, 256, 0, stream>>>(keys, Xb);
  proj_gemm<1><<<256, 512, 0, stream>>>(Xb, wkb, bk, (void*)A);
  // V projection
  conv_bf16<<<GRID_IN, 256, 0, stream>>>(values, Xb);
  proj_gemm<2><<<256, 512, 0, stream>>>(Xb, wvb, bv, (void*)Bb);
  // kv + z (part/zpart alias the dead Xb slab)
  kv_stage1<<<512, 256, 0, stream>>>(A, Bb, part, zpart);
  kv_stage2<<<64, 256, 0, stream>>>(part, zpart, kvb, z);
  // Q projection (kt/vt dead; reuse buffers)
  conv_bf16<<<GRID_IN, 256, 0, stream>>>(queries, Bb);
  proj_gemm<0><<<256, 512, 0, stream>>>(Bb, wqb, bq, (void*)A);
  // attention (in place over q)
  attn_kernel<<<1024, 256, 0, stream>>>(A, kvb, z, A);
  // output projection
  proj_gemm<3><<<256, 512, 0, stream>>>(A, wob, bo, d_out);
}